// Round 6
// baseline (357.756 us; speedup 1.0000x reference)
//
#include <hip/hip_runtime.h>
#include <hip/hip_bf16.h>

#define SEQ_T 100
#define HID 20
#define EMB_D 50
#define ROWP 64          // tab row stride (floats): gate cols [z20|r20|h20|pad4=0]
#define VOCAB_N 50000

__device__ __forceinline__ float ldf(const void* p, int i, int isf) {
  return isf ? ((const float*)p)[i]
             : __bfloat162float(((const __hip_bfloat16*)p)[i]);
}
// broadcast lane l's value into an SGPR (wave-uniform)
__device__ __forceinline__ float rdl(float v, int l) {
  return __uint_as_float(__builtin_amdgcn_readlane(__float_as_uint(v), l));
}
__device__ __forceinline__ float sigmoid_f(float x) {
  return __builtin_amdgcn_rcpf(1.f + __expf(-x));
}
__device__ __forceinline__ float tanh_f(float x) {
  return 1.f - 2.f * __builtin_amdgcn_rcpf(1.f + __expf(2.f * x));
}
// fp32 data read as u16 halfwords has uniform-random bf16-exponent fields
// (>=140 w.p. ~0.45 per low half); bf16 N(0,0.05) never exceeds ~125.
__device__ __forceinline__ int detect_isf(const void* emb) {
  uint4 dv = ((const uint4*)emb)[threadIdx.x & 63];
  int big = 0;
#pragma unroll
  for (int i = 0; i < 4; ++i) {
    unsigned w = ((const unsigned*)&dv)[i];
    big |= (((w >> 7) & 0xFF) >= 140) | (((w >> 23) & 0xFF) >= 140);
  }
  return (__ballot(big) != 0ull) ? 1 : 0;
}

// Force 20 floats to stay resident in VGPRs across loop iterations: the asm
// REDEFINES them each iteration, so the compiler cannot re-materialize them
// by reloading from memory (the round-3/round-5 killer: VGPR_Count=40 proved
// MachineLICM was sinking 60 loop-invariant weight loads into the hot loop).
#define PIN20(a) asm volatile("" \
  : "+v"(a[0]),"+v"(a[1]),"+v"(a[2]),"+v"(a[3]),"+v"(a[4]), \
    "+v"(a[5]),"+v"(a[6]),"+v"(a[7]),"+v"(a[8]),"+v"(a[9]), \
    "+v"(a[10]),"+v"(a[11]),"+v"(a[12]),"+v"(a[13]),"+v"(a[14]), \
    "+v"(a[15]),"+v"(a[16]),"+v"(a[17]),"+v"(a[18]),"+v"(a[19]))

// tab[v][col] = bi1[col] + sum_k emb[v][k]*W1[k][col]; fp32, 64-col rows.
// 1024 fat waves; W1 column resident in 50 VGPRs/lane; ~49 rows per wave;
// emb-row reads are wave-uniform -> scalar loads on the SMEM pipe.
__global__ __launch_bounds__(256) void build_table(
    const void* __restrict__ emb, const void* __restrict__ W1,
    const void* __restrict__ b1, float* __restrict__ tab)
{
  const int isf = detect_isf(emb);
  const int l = threadIdx.x & 63;
  const int wid = (blockIdx.x << 2) + (threadIdx.x >> 6);
  const int NW = gridDim.x << 2;
  const int jc = l < 60 ? l : 0;
  float w1c[EMB_D];
#pragma unroll
  for (int k = 0; k < EMB_D; ++k) w1c[k] = ldf(W1, k * 60 + jc, isf);
  const float bias = ldf(b1, jc, isf);

  for (int v = wid; v < VOCAB_N; v += NW) {
    float a = bias;
    if (isf) {
      const float* er = (const float*)emb + (size_t)v * EMB_D;
#pragma unroll
      for (int k = 0; k < EMB_D; ++k) a = fmaf(er[k], w1c[k], a);
    } else {
      const unsigned short* er = (const unsigned short*)emb + (size_t)v * EMB_D;
#pragma unroll
      for (int k = 0; k < EMB_D; k += 2) {
        unsigned u = *(const unsigned*)(er + k);
        a = fmaf(__uint_as_float(u << 16), w1c[k], a);
        a = fmaf(__uint_as_float(u & 0xffff0000u), w1c[k + 1], a);
      }
    }
    tab[(size_t)v * ROWP + l] = (l < 60) ? a : 0.f;
  }
}

// ONE batch element per wave; lane j<60 owns gate column j (z|r|h).
// 60 weight VGPRs pinned resident (PIN20); h-state = 40 readlane-born SGPRs.
// Matvecs: v_fma with SGPR h-operand x VGPR weight. Zero LDS staging.
__global__ __launch_bounds__(256, 4) void gru_main(
    const int* __restrict__ x, const float* __restrict__ tab,
    const void* __restrict__ emb,
    const void* __restrict__ U1, const void* __restrict__ b1,
    const void* __restrict__ W2, const void* __restrict__ U2,
    const void* __restrict__ b2, const void* __restrict__ Wd,
    const void* __restrict__ bd, void* __restrict__ out)
{
  const int isf = detect_isf(emb);
  const int j = threadIdx.x & 63;
  const int e = blockIdx.x * 4 + (threadIdx.x >> 6);
  const int jc = j < 60 ? j : 0;

  float wU1[HID], wW2[HID], wU2[HID];
#pragma unroll
  for (int k = 0; k < HID; ++k) {
    wU1[k] = ldf(U1, k * 60 + jc, isf);
    wW2[k] = ldf(W2, k * 60 + jc, isf);
    wU2[k] = ldf(U2, k * 60 + jc, isf);
  }
  const float br1 = ldf(b1, 60 + jc, isf);
  const float bi2 = ldf(b2, jc, isf);
  const float br2 = ldf(b2, 60 + jc, isf);

  float s1[HID], s2[HID];            // wave-uniform h (SGPRs via readlane)
#pragma unroll
  for (int k = 0; k < HID; ++k) { s1[k] = 0.f; s2[k] = 0.f; }
  float h1v = 0.f, h2v = 0.f;        // own-lane h copy (lanes 0..19)

  const int* __restrict__ xr = x + (size_t)e * SEQ_T;
  const float* __restrict__ tb = tab + j;

  // 2-deep pipelined input-transform gather
  float mx0 = tb[(size_t)xr[0] * ROWP];
  float mx1 = tb[(size_t)xr[1] * ROWP];

#pragma unroll 1
  for (int t = 0; t < SEQ_T; ++t) {
    PIN20(wU1); PIN20(wW2); PIN20(wU2);   // keep weights VGPR-resident

    float mx = mx0;
    mx0 = mx1;
    if (t + 2 < SEQ_T) mx1 = tb[(size_t)xr[t + 2] * ROWP];

    // ---- GRU1: mh = h1 @ U1 + br1 ----
    float mh = br1;
#pragma unroll
    for (int k = 0; k < HID; ++k) mh = fmaf(s1[k], wU1[k], mh);
    float g  = sigmoid_f(mx + mh);          // z (lanes 0..19), r (20..39)
    float rr = __shfl(g, j - 20);           // h-lanes (40..59) fetch r
    float hc = tanh_f(fmaf(rr, mh, mx));    // xh + r*(h@U_h + br_h)
    float hv = __shfl(hc, j + 40);          // z-lanes fetch hcand
    h1v = fmaf(g, h1v - hv, hv);            // z*h + (1-z)*hc, lanes 0..19
#pragma unroll
    for (int k = 0; k < HID; ++k) s1[k] = rdl(h1v, k);

    // ---- GRU2: mx2 = h1new @ W2 + bi2 ; mh2 = h2 @ U2 + br2 ----
    float m2 = bi2, n2 = br2;
#pragma unroll
    for (int k = 0; k < HID; ++k) {
      m2 = fmaf(s1[k], wW2[k], m2);
      n2 = fmaf(s2[k], wU2[k], n2);
    }
    float g2  = sigmoid_f(m2 + n2);
    float rr2 = __shfl(g2, j - 20);
    float hc2 = tanh_f(fmaf(rr2, n2, m2));
    float hv2 = __shfl(hc2, j + 40);
    h2v = fmaf(g2, h2v - hv2, hv2);
#pragma unroll
    for (int k = 0; k < HID; ++k) s2[k] = rdl(h2v, k);
  }

  // ---- dense: logits = h2 @ Wd + bd (h2 wave-uniform in SGPRs) ----
  if (j < 15) {
    float a = ldf(bd, j, isf);
#pragma unroll
    for (int k = 0; k < HID; ++k)
      a = fmaf(s2[k], ldf(Wd, k * 15 + j, isf), a);
    if (isf) ((float*)out)[(size_t)e * 15 + j] = a;
    else ((__hip_bfloat16*)out)[(size_t)e * 15 + j] = __float2bfloat16(a);
  }
}

extern "C" void kernel_launch(void* const* d_in, const int* in_sizes, int n_in,
                              void* d_out, int out_size, void* d_ws, size_t ws_size,
                              hipStream_t stream) {
  const int* x    = (const int*)d_in[0];
  const void* emb = d_in[1];
  const void* W1  = d_in[2];
  const void* U1  = d_in[3];
  const void* b1  = d_in[4];
  const void* W2  = d_in[5];
  const void* U2  = d_in[6];
  const void* b2  = d_in[7];
  const void* Wd  = d_in[8];
  const void* bd  = d_in[9];
  float* tab = (float*)d_ws;   // 50000*64*4 = 12.8 MB

  build_table<<<256, 256, 0, stream>>>(emb, W1, b1, tab);
  // 8192 waves, 1 element each; 4 waves per 256-thread block
  gru_main<<<8192 / 4, 256, 0, stream>>>(x, tab, emb, U1, b1, W2, U2, b2,
                                         Wd, bd, d_out);
}

// Round 7
// 296.830 us; speedup vs baseline: 1.2053x; 1.2053x over previous
//
#include <hip/hip_runtime.h>
#include <hip/hip_bf16.h>

#define SEQ_T 100
#define HID 20
#define EMB_D 50
#define VOCAB_N 50000
#define TABW 60          // tab row = 60 gate cols [z20|r20|h20], no pad

typedef short sh8 __attribute__((ext_vector_type(8)));   // 8 bf16 bit patterns
typedef float f4  __attribute__((ext_vector_type(4)));

// ws layout (float offsets): fp32 weight copies first, then the mx table.
#define OFF_U1 0
#define OFF_B1 1200
#define OFF_W2 1320
#define OFF_U2 2520
#define OFF_B2 3720
#define OFF_WD 3840
#define OFF_BD 4140
#define OFF_TAB 4160     // 50000*60 floats -> total ws use ~12.02 MB

__device__ __forceinline__ float ldf(const void* p, int i, int isf) {
  return isf ? ((const float*)p)[i]
             : __bfloat162float(((const __hip_bfloat16*)p)[i]);
}
__device__ __forceinline__ short f2bf(float f) {   // RNE fp32->bf16 bits
  unsigned u = __float_as_uint(f);
  u += 0x7fffu + ((u >> 16) & 1u);
  return (short)(u >> 16);
}
__device__ __forceinline__ float rdl(float v, int l) {
  return __uint_as_float(__builtin_amdgcn_readlane(__float_as_uint(v), l));
}
__device__ __forceinline__ float sigmoid_f(float x) {
  return __builtin_amdgcn_rcpf(1.f + __expf(-x));
}
__device__ __forceinline__ float tanh_f(float x) {
  return 1.f - 2.f * __builtin_amdgcn_rcpf(1.f + __expf(2.f * x));
}
// fp32 data read as u16 halfwords has uniform-random bf16-exponent fields
// (>=140 w.p. ~0.45 per low half); bf16 N(0,0.05) never exceeds ~125.
__device__ __forceinline__ int detect_isf(const void* emb) {
  uint4 dv = ((const uint4*)emb)[threadIdx.x & 63];
  int big = 0;
#pragma unroll
  for (int i = 0; i < 4; ++i) {
    unsigned w = ((const unsigned*)&dv)[i];
    big |= (((w >> 7) & 0xFF) >= 140) | (((w >> 23) & 0xFF) >= 140);
  }
  return (__ballot(big) != 0ull) ? 1 : 0;
}

// Convert all recurrent/dense weights+biases to fp32 in ws (removes the
// per-step bf16-unpack and runtime-dtype select from the hot loop).
__global__ __launch_bounds__(256) void prep_weights(
    const void* __restrict__ emb,
    const void* __restrict__ U1, const void* __restrict__ b1,
    const void* __restrict__ W2, const void* __restrict__ U2,
    const void* __restrict__ b2, const void* __restrict__ Wd,
    const void* __restrict__ bd, float* __restrict__ ws)
{
  const int isf = detect_isf(emb);
  const int t = threadIdx.x;
  for (int i = t; i < 1200; i += 256) ws[OFF_U1 + i] = ldf(U1, i, isf);
  for (int i = t; i < 120;  i += 256) ws[OFF_B1 + i] = ldf(b1, i, isf);
  for (int i = t; i < 1200; i += 256) ws[OFF_W2 + i] = ldf(W2, i, isf);
  for (int i = t; i < 1200; i += 256) ws[OFF_U2 + i] = ldf(U2, i, isf);
  for (int i = t; i < 120;  i += 256) ws[OFF_B2 + i] = ldf(b2, i, isf);
  for (int i = t; i < 300;  i += 256) ws[OFF_WD + i] = ldf(Wd, i, isf);
  for (int i = t; i < 15;   i += 256) ws[OFF_BD + i] = ldf(bd, i, isf);
}

// tab = emb @ W1 + bi1 as a real GEMM on the matrix cores.
// M=50000 (3125 16-row tiles), N=60->64, K=50->64 (2 k-tiles of 32).
// bf16 inputs => MFMA products are EXACT (fp32 accumulate); fp32 inputs get
// rounded to bf16 (path not expected to trigger; data is bf16).
__global__ __launch_bounds__(256) void build_table(
    const void* __restrict__ emb, const void* __restrict__ W1,
    const void* __restrict__ b1, float* __restrict__ ws)
{
  const int isf = detect_isf(emb);
  const int L = threadIdx.x & 63, q = L >> 4, c = L & 15;
  const int tile = blockIdx.x * 4 + (threadIdx.x >> 6);
  if (tile >= VOCAB_N / 16) return;          // 3125 tiles, exact
  const int v0 = tile * 16;
  float* __restrict__ tab = ws + OFF_TAB;

  // A-frags: A[m=lane&15][k=quad*8+j]; row v0+c, k-tile0 = 0..31, tile1 = 32..63
  sh8 A0, A1;
#pragma unroll
  for (int j = 0; j < 8; ++j) { A0[j] = 0; A1[j] = 0; }
  if (!isf) {
    const unsigned short* eb = (const unsigned short*)emb;
    const size_t rb = (size_t)(v0 + c) * EMB_D;
    // dword loads only: row stride is 100 B, 16B alignment not guaranteed
#pragma unroll
    for (int i = 0; i < 4; ++i) {
      unsigned d = *(const unsigned*)(eb + rb + q * 8 + 2 * i);
      A0[2 * i] = (short)(d & 0xffff); A0[2 * i + 1] = (short)(d >> 16);
    }
    const int k1b = 32 + q * 8;
#pragma unroll
    for (int i = 0; i < 4; ++i) {
      const int k = k1b + 2 * i;
      if (k + 1 < EMB_D) {               // q=0,1 full; q=2 first dword only
        unsigned d = *(const unsigned*)(eb + rb + k);
        A1[2 * i] = (short)(d & 0xffff); A1[2 * i + 1] = (short)(d >> 16);
      }
    }
  } else {
    const float* ef = (const float*)emb;
    const size_t rb = (size_t)(v0 + c) * EMB_D;
#pragma unroll
    for (int j = 0; j < 8; ++j) {
      const int k0 = q * 8 + j, k1 = 32 + q * 8 + j;
      A0[j] = f2bf(ef[rb + k0]);
      A1[j] = (k1 < EMB_D) ? f2bf(ef[rb + k1]) : (short)0;
    }
  }

  // per n-tile: B[k=quad*8+j][n=lane&15], bias-splatted acc, 2 MFMA, store
#pragma unroll
  for (int nt = 0; nt < 4; ++nt) {
    const int col = nt * 16 + c;
    sh8 B0, B1;
#pragma unroll
    for (int j = 0; j < 8; ++j) {
      const int k0 = q * 8 + j, k1 = 32 + q * 8 + j;
      B0[j] = (col < TABW) ? f2bf(ldf(W1, k0 * TABW + col, isf)) : (short)0;
      B1[j] = (col < TABW && k1 < EMB_D)
                  ? f2bf(ldf(W1, k1 * TABW + col, isf)) : (short)0;
    }
    const float bi = (col < TABW) ? ldf(b1, col, isf) : 0.f;
    f4 acc = { bi, bi, bi, bi };
    acc = __builtin_amdgcn_mfma_f32_16x16x32_bf16(A0, B0, acc, 0, 0, 0);
    acc = __builtin_amdgcn_mfma_f32_16x16x32_bf16(A1, B1, acc, 0, 0, 0);
    if (col < TABW) {
      // C/D: col=lane&15, row=quad*4+reg
#pragma unroll
      for (int r = 0; r < 4; ++r)
        tab[(size_t)(v0 + q * 4 + r) * TABW + col] = acc[r];
    }
  }
}

#define F20(X) X(0) X(1) X(2) X(3) X(4) X(5) X(6) X(7) X(8) X(9) \
  X(10) X(11) X(12) X(13) X(14) X(15) X(16) X(17) X(18) X(19)
// one-shot pin: values become asm-defined => not rematerializable-by-reload
#define PINA(p) asm("" : "+v"(p##_0),"+v"(p##_1),"+v"(p##_2),"+v"(p##_3), \
  "+v"(p##_4),"+v"(p##_5),"+v"(p##_6),"+v"(p##_7),"+v"(p##_8),"+v"(p##_9), \
  "+v"(p##_10),"+v"(p##_11),"+v"(p##_12),"+v"(p##_13),"+v"(p##_14), \
  "+v"(p##_15),"+v"(p##_16),"+v"(p##_17),"+v"(p##_18),"+v"(p##_19))

// ONE batch element per wave; lane j<60 owns gate col j (z|r|h).
// Weights: 60 NAMED fp32 scalars (no arrays -> nothing to scratch-demote),
// pinned once before the loop. h-state: 40 readlane-born SGPRs.
__global__ __launch_bounds__(256, 4) void gru_main(
    const int* __restrict__ x, const float* __restrict__ ws,
    const void* __restrict__ emb, void* __restrict__ out)
{
  const int isf = detect_isf(emb);   // output dtype only
  const int j = threadIdx.x & 63;
  const int e = blockIdx.x * 4 + (threadIdx.x >> 6);
  const int jc = j < TABW ? j : 0;

  const float* __restrict__ Uf = ws + OFF_U1;
  const float* __restrict__ Wf = ws + OFF_W2;
  const float* __restrict__ Vf = ws + OFF_U2;
  const float* __restrict__ tab = ws + OFF_TAB;

#define DW(k) float u1_##k = Uf[k * TABW + jc]; \
              float w2_##k = Wf[k * TABW + jc]; \
              float v2_##k = Vf[k * TABW + jc];
  F20(DW)
#undef DW
  const float br1 = ws[OFF_B1 + 60 + jc];
  const float bi2 = ws[OFF_B2 + jc];
  const float br2 = ws[OFF_B2 + 60 + jc];
  PINA(u1); PINA(w2); PINA(v2);

#define DS(k) float s1_##k = 0.f, s2_##k = 0.f;
  F20(DS)
#undef DS
  float h1v = 0.f, h2v = 0.f;        // own-lane h copy (lanes 0..19)

  const int* __restrict__ xr = x + (size_t)e * SEQ_T;
  float mx0 = tab[(size_t)xr[0] * TABW + jc];
  float mx1 = tab[(size_t)xr[1] * TABW + jc];

#pragma unroll 1
  for (int t = 0; t < SEQ_T; ++t) {
    float mx = mx0; mx0 = mx1;
    if (t + 2 < SEQ_T) mx1 = tab[(size_t)xr[t + 2] * TABW + jc];

    // ---- GRU1: mh = h1 @ U1 + br1 (SGPR h x pinned VGPR w) ----
    float mh = br1;
#define MH(k) mh = fmaf(s1_##k, u1_##k, mh);
    F20(MH)
#undef MH
    float g  = sigmoid_f(mx + mh);          // z (lanes 0..19), r (20..39)
    float rr = __shfl(g, j - 20);           // h-lanes fetch r
    float hc = tanh_f(fmaf(rr, mh, mx));    // xh + r*(h@U_h + br_h)
    float hv = __shfl(hc, j + 40);          // z-lanes fetch hcand
    h1v = fmaf(g, h1v - hv, hv);            // z*h + (1-z)*hc
#define RS(k) s1_##k = rdl(h1v, k);
    F20(RS)
#undef RS

    // ---- GRU2: mx2 = h1new @ W2 + bi2 ; mh2 = h2 @ U2 + br2 ----
    float m2 = bi2, n2 = br2;
#define M2(k) m2 = fmaf(s1_##k, w2_##k, m2); n2 = fmaf(s2_##k, v2_##k, n2);
    F20(M2)
#undef M2
    float g2  = sigmoid_f(m2 + n2);
    float rr2 = __shfl(g2, j - 20);
    float hc2 = tanh_f(fmaf(rr2, n2, m2));
    float hv2 = __shfl(hc2, j + 40);
    h2v = fmaf(g2, h2v - hv2, hv2);
#define RS2(k) s2_##k = rdl(h2v, k);
    F20(RS2)
#undef RS2
  }

  // ---- dense: logits = h2 @ Wd + bd (h2 wave-uniform in SGPRs) ----
  if (j < 15) {
    float a = ws[OFF_BD + j];
#define DE(k) a = fmaf(s2_##k, ws[OFF_WD + k * 15 + j], a);
    F20(DE)
#undef DE
    if (isf) ((float*)out)[(size_t)e * 15 + j] = a;
    else ((__hip_bfloat16*)out)[(size_t)e * 15 + j] = __float2bfloat16(a);
  }
}

extern "C" void kernel_launch(void* const* d_in, const int* in_sizes, int n_in,
                              void* d_out, int out_size, void* d_ws, size_t ws_size,
                              hipStream_t stream) {
  const int* x    = (const int*)d_in[0];
  const void* emb = d_in[1];
  const void* W1  = d_in[2];
  const void* U1  = d_in[3];
  const void* b1  = d_in[4];
  const void* W2  = d_in[5];
  const void* U2  = d_in[6];
  const void* b2  = d_in[7];
  const void* Wd  = d_in[8];
  const void* bd  = d_in[9];
  float* ws = (float*)d_ws;   // ~12.02 MB used (< round-2-proven 12.8 MB)

  prep_weights<<<1, 256, 0, stream>>>(emb, U1, b1, W2, U2, b2, Wd, bd, ws);
  build_table<<<(VOCAB_N / 16 + 3) / 4, 256, 0, stream>>>(emb, W1, b1, ws);
  gru_main<<<8192 / 4, 256, 0, stream>>>(x, ws, emb, d_out);
}

// Round 8
// 277.430 us; speedup vs baseline: 1.2895x; 1.0699x over previous
//
#include <hip/hip_runtime.h>
#include <hip/hip_bf16.h>

#define SEQ_T 100
#define HID 20
#define EMB_D 50
#define VOCAB_N 50000
#define TABW 60          // tab row = 60 gate cols [z20|r20|h20]

typedef short sh8 __attribute__((ext_vector_type(8)));   // 8 bf16 bit patterns
typedef float f4  __attribute__((ext_vector_type(4)));

// ws layout (float offsets): fp32 weight copies first, then the mx table.
#define OFF_U1 0
#define OFF_B1 1200
#define OFF_W2 1320
#define OFF_U2 2520
#define OFF_B2 3720
#define OFF_WD 3840
#define OFF_BD 4140
#define OFF_TAB 4160     // 50000*60 floats -> total ws use ~12.02 MB

__device__ __forceinline__ float ldf(const void* p, int i, int isf) {
  return isf ? ((const float*)p)[i]
             : __bfloat162float(((const __hip_bfloat16*)p)[i]);
}
__device__ __forceinline__ short f2bf(float f) {   // RNE fp32->bf16 bits
  unsigned u = __float_as_uint(f);
  u += 0x7fffu + ((u >> 16) & 1u);
  return (short)(u >> 16);
}
__device__ __forceinline__ float rdl(float v, int l) {
  return __uint_as_float(__builtin_amdgcn_readlane(__float_as_uint(v), l));
}
__device__ __forceinline__ float sigmoid_f(float x) {
  return __builtin_amdgcn_rcpf(1.f + __expf(-x));
}
__device__ __forceinline__ float tanh_f(float x) {
  return 1.f - 2.f * __builtin_amdgcn_rcpf(1.f + __expf(2.f * x));
}
// fp32 data read as u16 halfwords has uniform-random bf16-exponent fields
// (>=140 w.p. ~0.45 per low half); bf16 N(0,0.05) never exceeds ~125.
__device__ __forceinline__ int detect_isf(const void* emb) {
  uint4 dv = ((const uint4*)emb)[threadIdx.x & 63];
  int big = 0;
#pragma unroll
  for (int i = 0; i < 4; ++i) {
    unsigned w = ((const unsigned*)&dv)[i];
    big |= (((w >> 7) & 0xFF) >= 140) | (((w >> 23) & 0xFF) >= 140);
  }
  return (__ballot(big) != 0ull) ? 1 : 0;
}

// tab = emb @ W1 + bi1 on the matrix cores (M=50000, N=60->64, K=50->64).
// bf16 inputs => MFMA products are EXACT (fp32 accumulate). Block 0 also
// converts all recurrent/dense weights+biases to fp32 in ws (prep fold).
__global__ __launch_bounds__(256) void build_table(
    const void* __restrict__ emb, const void* __restrict__ W1,
    const void* __restrict__ b1,
    const void* __restrict__ U1, const void* __restrict__ W2,
    const void* __restrict__ U2, const void* __restrict__ b2,
    const void* __restrict__ Wd, const void* __restrict__ bd,
    float* __restrict__ ws)
{
  const int isf = detect_isf(emb);
  if (blockIdx.x == 0) {                     // fold: weight fp32 prep
    const int t = threadIdx.x;
    for (int i = t; i < 1200; i += 256) {
      ws[OFF_U1 + i] = ldf(U1, i, isf);
      ws[OFF_W2 + i] = ldf(W2, i, isf);
      ws[OFF_U2 + i] = ldf(U2, i, isf);
    }
    for (int i = t; i < 120; i += 256) {
      ws[OFF_B1 + i] = ldf(b1, i, isf);
      ws[OFF_B2 + i] = ldf(b2, i, isf);
    }
    for (int i = t; i < 300; i += 256) ws[OFF_WD + i] = ldf(Wd, i, isf);
    for (int i = t; i < 15;  i += 256) ws[OFF_BD + i] = ldf(bd, i, isf);
  }

  const int L = threadIdx.x & 63, q = L >> 4, c = L & 15;
  const int tile = blockIdx.x * 4 + (threadIdx.x >> 6);
  if (tile >= VOCAB_N / 16) return;          // 3125 tiles, exact
  const int v0 = tile * 16;
  float* __restrict__ tab = ws + OFF_TAB;

  // A-frags: A[m=lane&15][k=quad*8+j]; row v0+c; k-tiles 0..31 / 32..63
  sh8 A0, A1;
#pragma unroll
  for (int j = 0; j < 8; ++j) { A0[j] = 0; A1[j] = 0; }
  if (!isf) {
    const unsigned short* eb = (const unsigned short*)emb;
    const size_t rb = (size_t)(v0 + c) * EMB_D;
#pragma unroll
    for (int i = 0; i < 4; ++i) {            // dword loads: rows are 100 B
      unsigned d = *(const unsigned*)(eb + rb + q * 8 + 2 * i);
      A0[2 * i] = (short)(d & 0xffff); A0[2 * i + 1] = (short)(d >> 16);
    }
    const int k1b = 32 + q * 8;
#pragma unroll
    for (int i = 0; i < 4; ++i) {
      const int k = k1b + 2 * i;
      if (k + 1 < EMB_D) {                   // q=0,1 full; q=2 partial
        unsigned d = *(const unsigned*)(eb + rb + k);
        A1[2 * i] = (short)(d & 0xffff); A1[2 * i + 1] = (short)(d >> 16);
      }
    }
  } else {
    const float* ef = (const float*)emb;
    const size_t rb = (size_t)(v0 + c) * EMB_D;
#pragma unroll
    for (int j = 0; j < 8; ++j) {
      const int k0 = q * 8 + j, k1 = 32 + q * 8 + j;
      A0[j] = f2bf(ef[rb + k0]);
      A1[j] = (k1 < EMB_D) ? f2bf(ef[rb + k1]) : (short)0;
    }
  }

#pragma unroll
  for (int nt = 0; nt < 4; ++nt) {
    const int col = nt * 16 + c;
    sh8 B0, B1;
#pragma unroll
    for (int j = 0; j < 8; ++j) {            // B[k=quad*8+j][n=lane&15]
      const int k0 = q * 8 + j, k1 = 32 + q * 8 + j;
      B0[j] = (col < TABW) ? f2bf(ldf(W1, k0 * TABW + col, isf)) : (short)0;
      B1[j] = (col < TABW && k1 < EMB_D)
                  ? f2bf(ldf(W1, k1 * TABW + col, isf)) : (short)0;
    }
    const float bi = (col < TABW) ? ldf(b1, col, isf) : 0.f;
    f4 acc = { bi, bi, bi, bi };
    acc = __builtin_amdgcn_mfma_f32_16x16x32_bf16(A0, B0, acc, 0, 0, 0);
    acc = __builtin_amdgcn_mfma_f32_16x16x32_bf16(A1, B1, acc, 0, 0, 0);
    if (col < TABW) {                        // C/D: col=lane&15, row=q*4+reg
#pragma unroll
      for (int r = 0; r < 4; ++r)
        tab[(size_t)(v0 + q * 4 + r) * TABW + col] = acc[r];
    }
  }
}

#define F20(X) X(0) X(1) X(2) X(3) X(4) X(5) X(6) X(7) X(8) X(9) \
  X(10) X(11) X(12) X(13) X(14) X(15) X(16) X(17) X(18) X(19)
// Assert VGPR residency of a 20-scalar group. Placed INSIDE the loop, the RA
// must either keep all 60 weights resident or pay 120 fill/spill ops per
// iteration -- flipping the cost balance that made it spill in rounds 5-7.
#define PINA(p) asm volatile("" : "+v"(p##_0),"+v"(p##_1),"+v"(p##_2), \
  "+v"(p##_3),"+v"(p##_4),"+v"(p##_5),"+v"(p##_6),"+v"(p##_7),"+v"(p##_8), \
  "+v"(p##_9),"+v"(p##_10),"+v"(p##_11),"+v"(p##_12),"+v"(p##_13), \
  "+v"(p##_14),"+v"(p##_15),"+v"(p##_16),"+v"(p##_17),"+v"(p##_18),"+v"(p##_19))

// ONE batch element per wave, ONE wave per block (round-4 precedent: only
// 64-thread blocks + explicit min-waves get a big VGPR allocation from the
// AMDGPU RA). Lane j<60 owns gate col j (z|r|h). Weights: 60 named fp32
// scalars pinned every iteration. h-state: 40 readlane-born SGPRs.
__global__ __launch_bounds__(64, 3) void gru_main(
    const int* __restrict__ x, const float* __restrict__ ws,
    const void* __restrict__ emb, void* __restrict__ out)
{
  const int isf = detect_isf(emb);   // output dtype only
  const int j = threadIdx.x & 63;
  const int e = blockIdx.x;
  const int jc = j < TABW ? j : 0;

  const float* __restrict__ Uf = ws + OFF_U1;
  const float* __restrict__ Wf = ws + OFF_W2;
  const float* __restrict__ Vf = ws + OFF_U2;
  const float* __restrict__ tab = ws + OFF_TAB;

#define DW(k) float u1_##k = Uf[k * TABW + jc]; \
              float w2_##k = Wf[k * TABW + jc]; \
              float v2_##k = Vf[k * TABW + jc];
  F20(DW)
#undef DW
  const float br1 = ws[OFF_B1 + 60 + jc];
  const float bi2 = ws[OFF_B2 + jc];
  const float br2 = ws[OFF_B2 + 60 + jc];

#define DS(k) float s1_##k = 0.f, s2_##k = 0.f;
  F20(DS)
#undef DS
  float h1v = 0.f, h2v = 0.f;        // own-lane h copy (lanes 0..19)

  const int* __restrict__ xr = x + (size_t)e * SEQ_T;
  float mx0 = tab[(size_t)xr[0] * TABW + jc];
  float mx1 = tab[(size_t)xr[1] * TABW + jc];

#pragma unroll 1
  for (int t = 0; t < SEQ_T; ++t) {
    PINA(u1); PINA(w2); PINA(v2);    // all 60 live HERE, every iteration

    float mx = mx0; mx0 = mx1;
    if (t + 2 < SEQ_T) mx1 = tab[(size_t)xr[t + 2] * TABW + jc];

    // ---- GRU1: mh = h1 @ U1 + br1 (SGPR h x pinned VGPR w) ----
    float mh = br1;
#define MH(k) mh = fmaf(s1_##k, u1_##k, mh);
    F20(MH)
#undef MH
    float g  = sigmoid_f(mx + mh);          // z (lanes 0..19), r (20..39)
    float rr = __shfl(g, j - 20);           // h-lanes fetch r
    float hc = tanh_f(fmaf(rr, mh, mx));    // xh + r*(h@U_h + br_h)
    float hv = __shfl(hc, j + 40);          // z-lanes fetch hcand
    h1v = fmaf(g, h1v - hv, hv);            // z*h + (1-z)*hc
#define RS(k) s1_##k = rdl(h1v, k);
    F20(RS)
#undef RS

    // ---- GRU2: mx2 = h1new @ W2 + bi2 ; mh2 = h2 @ U2 + br2 ----
    float m2 = bi2, n2 = br2;
#define M2(k) m2 = fmaf(s1_##k, w2_##k, m2); n2 = fmaf(s2_##k, v2_##k, n2);
    F20(M2)
#undef M2
    float g2  = sigmoid_f(m2 + n2);
    float rr2 = __shfl(g2, j - 20);
    float hc2 = tanh_f(fmaf(rr2, n2, m2));
    float hv2 = __shfl(hc2, j + 40);
    h2v = fmaf(g2, h2v - hv2, hv2);
#define RS2(k) s2_##k = rdl(h2v, k);
    F20(RS2)
#undef RS2
  }

  // ---- dense: logits = h2 @ Wd + bd (h2 wave-uniform in SGPRs) ----
  if (j < 15) {
    float a = ws[OFF_BD + j];
#define DE(k) a = fmaf(s2_##k, ws[OFF_WD + k * 15 + j], a);
    F20(DE)
#undef DE
    if (isf) ((float*)out)[(size_t)e * 15 + j] = a;
    else ((__hip_bfloat16*)out)[(size_t)e * 15 + j] = __float2bfloat16(a);
  }
}

extern "C" void kernel_launch(void* const* d_in, const int* in_sizes, int n_in,
                              void* d_out, int out_size, void* d_ws, size_t ws_size,
                              hipStream_t stream) {
  const int* x    = (const int*)d_in[0];
  const void* emb = d_in[1];
  const void* W1  = d_in[2];
  const void* U1  = d_in[3];
  const void* b1  = d_in[4];
  const void* W2  = d_in[5];
  const void* U2  = d_in[6];
  const void* b2  = d_in[7];
  const void* Wd  = d_in[8];
  const void* bd  = d_in[9];
  float* ws = (float*)d_ws;   // ~12.02 MB used

  build_table<<<(VOCAB_N / 16 + 3) / 4, 256, 0, stream>>>(
      emb, W1, b1, U1, W2, U2, b2, Wd, bd, ws);
  gru_main<<<8192, 64, 0, stream>>>(x, ws, emb, d_out);
}